// Round 1
// baseline (308.660 us; speedup 1.0000x reference)
//
#include <hip/hip_runtime.h>
#include <math.h>

#define G 16  // tokens per round; LDS = 16*4KB x + ~2.6KB small = ~68KB -> 2 blocks/CU

__device__ __forceinline__ float sigmoidf_(float s) {
    return 1.0f / (1.0f + __expf(-s));
}

// Pair-fold reduction step: lanes with (l&m)==0 get X(l)+X(l^m),
// lanes with (l&m)!=0 get Y(l)+Y(l^m).
__device__ __forceinline__ float fold_(float X, float Y, int m, int l) {
    const bool hi = (l & m) != 0;
    const float a = hi ? Y : X;
    const float b = hi ? X : Y;
    return a + __shfl_xor(b, m);
}

__global__ __launch_bounds__(256, 2)
void fused_route_mix(const float* __restrict__ x,
                     const float* __restrict__ scale,
                     const float* __restrict__ w_pre,
                     const float* __restrict__ w_post,
                     const float* __restrict__ w_res,
                     const float* __restrict__ ap_p,
                     const float* __restrict__ apo_p,
                     const float* __restrict__ ar_p,
                     const float* __restrict__ b_pre,
                     const float* __restrict__ b_post,
                     const float* __restrict__ b_res,
                     float* __restrict__ out,
                     int rounds)
{
    __shared__ __align__(16) float xs[G * 1024];   // raw x for G tokens
    __shared__ float hraw[G * 24];                 // 24 raw dots per token
    __shared__ float sslds[G];                     // sum of squares per token
    __shared__ __align__(16) float Mlds[G * 16];   // 4x4 mixing matrix per token

    const int t = threadIdx.x;
    const int w = t >> 6;   // wave 0..3
    const int l = t & 63;   // lane 0..63

    // ---- once per block: weight fragments in registers (scale folded in) ----
    // global row k: 0-3 = w_pre, 4-7 = w_post, 8-23 = w_res. wave w owns rows 6w..6w+5.
    // lane l owns elements {4*l + 256*mp + j : mp=0..3, j=0..3} -> float4 LDS reads.
    float wreg[6][16];
    {
        float scl[16];
        #pragma unroll
        for (int mp = 0; mp < 4; ++mp) {
            #pragma unroll
            for (int j = 0; j < 4; ++j)
                scl[4 * mp + j] = scale[4 * l + 256 * mp + j];
        }
        #pragma unroll
        for (int rr = 0; rr < 6; ++rr) {
            const int k = 6 * w + rr;
            const float* wp = (k < 4) ? (w_pre + (size_t)k * 1024)
                            : (k < 8) ? (w_post + (size_t)(k - 4) * 1024)
                                      : (w_res + (size_t)(k - 8) * 1024);
            #pragma unroll
            for (int mp = 0; mp < 4; ++mp)
                #pragma unroll
                for (int j = 0; j < 4; ++j)
                    wreg[rr][4 * mp + j] = wp[4 * l + 256 * mp + j] * scl[4 * mp + j];
        }
    }

    const float a_pre = ap_p[0], a_post = apo_p[0], a_res = ar_p[0];

    const int rstep = gridDim.x;

    // ---- prologue: prefetch first round into registers ----
    float4 pf[G];
    {
        const float4* __restrict__ xg =
            (const float4*)(x + (size_t)blockIdx.x * (G * 1024));
        #pragma unroll
        for (int i = 0; i < G; ++i) pf[i] = xg[i * 256 + t];
    }

    for (int r = blockIdx.x; r < rounds; r += rstep) {
        const size_t base = (size_t)r * (G * 1024);
        float4* xs4 = (float4*)xs;

        // ---- phase 1: spill prefetched x to LDS (vmcnt wait lands here) ----
        #pragma unroll
        for (int i = 0; i < G; ++i)
            xs4[i * 256 + t] = pf[i];
        __syncthreads();

        // ---- issue next round's loads; in flight through phase 2 ----
        const int rn = r + rstep;
        if (rn < rounds) {
            const float4* __restrict__ xg =
                (const float4*)(x + (size_t)rn * (G * 1024));
            #pragma unroll
            for (int i = 0; i < G; ++i) pf[i] = xg[i * 256 + t];
        }

        // ---- phase 2: 24 raw dot products + sum-of-squares per token ----
        for (int i = 0; i < G; ++i) {
            float p0 = 0.f, p1 = 0.f, p2 = 0.f, p3 = 0.f, p4 = 0.f, p5 = 0.f;
            float ss = 0.f;
            const float4* __restrict__ xi4 = (const float4*)(xs + i * 1024);
            #pragma unroll
            for (int mp = 0; mp < 4; ++mp) {
                const float4 xv = xi4[l + 64 * mp];   // ds_read_b128, conflict-free
                const float xe[4] = {xv.x, xv.y, xv.z, xv.w};
                #pragma unroll
                for (int j = 0; j < 4; ++j) {
                    const float xj = xe[j];
                    p0 = fmaf(xj, wreg[0][4 * mp + j], p0);
                    p1 = fmaf(xj, wreg[1][4 * mp + j], p1);
                    p2 = fmaf(xj, wreg[2][4 * mp + j], p2);
                    p3 = fmaf(xj, wreg[3][4 * mp + j], p3);
                    p4 = fmaf(xj, wreg[4][4 * mp + j], p4);
                    p5 = fmaf(xj, wreg[5][4 * mp + j], p5);
                    ss = fmaf(xj, xj, ss);            // same across waves; wave0 writes
                }
            }
            // pack-fold butterfly: 10 shfl instead of 42.
            // value class by lane bits after folds: b5 (step1), b4 (step2), b3 (step3)
            const float q0 = fold_(p0, p1, 32, l);
            const float q1 = fold_(p2, p3, 32, l);
            const float q2 = fold_(p4, p5, 32, l);
            const float q3 = ss + __shfl_xor(ss, 32);
            const float r0v = fold_(q0, q1, 16, l);
            const float r1v = fold_(q2, q3, 16, l);
            float s = fold_(r0v, r1v, 8, l);
            s += __shfl_xor(s, 4);
            s += __shfl_xor(s, 2);
            s += __shfl_xor(s, 1);
            // lanes 0,8,16,24,32,40,48 hold fully-reduced values:
            // vid: 0=p0(l0) 1=p1(l32) 2=p2(l16) 3=p3(l48) 4=p4(l8) 5=p5(l40) 6=ss(l24)
            if ((l & 7) == 0) {
                const int vid = ((l >> 3) & 1) * 4 + ((l >> 4) & 1) * 2 + ((l >> 5) & 1);
                if (vid < 6) hraw[i * 24 + 6 * w + vid] = s;
                else if (w == 0 && vid == 6) sslds[i] = s;
            }
        }
        __syncthreads();

        // ---- phase 3: per-token nonlinearity + sinkhorn (token-per-lane, wave 0) ----
        if (t < G) {
            const int tk = t;
            const float inv = rsqrtf(sslds[tk] * (1.0f / 1024.0f) + 1e-5f);
            float hr[24];
            #pragma unroll
            for (int k = 0; k < 24; ++k) hr[k] = hraw[tk * 24 + k];

            float hpre[4], hpost[4];
            #pragma unroll
            for (int j = 0; j < 4; ++j)
                hpre[j] = sigmoidf_(fmaf(a_pre * inv, hr[j], b_pre[j]));
            #pragma unroll
            for (int i = 0; i < 4; ++i)
                hpost[i] = 2.0f * sigmoidf_(fmaf(a_post * inv, hr[4 + i], b_post[i]));

            float K[4][4];
            float mx = -1e30f;
            #pragma unroll
            for (int i = 0; i < 4; ++i) {
                #pragma unroll
                for (int j = 0; j < 4; ++j) {
                    const float vv = fmaf(a_res * inv, hr[8 + 4 * i + j], b_res[4 * i + j]);
                    K[i][j] = vv;
                    mx = fmaxf(mx, vv);
                }
            }
            #pragma unroll
            for (int i = 0; i < 4; ++i)
                #pragma unroll
                for (int j = 0; j < 4; ++j)
                    K[i][j] = __expf(K[i][j] - mx);

            // sinkhorn as scaling vectors: matrix is u_i * K_ij * v_j throughout.
            float u[4] = {1.f, 1.f, 1.f, 1.f};
            float v[4] = {1.f, 1.f, 1.f, 1.f};
            for (int it = 0; it < 20; ++it) {
                #pragma unroll
                for (int j = 0; j < 4; ++j) {
                    const float S = u[0] * K[0][j] + u[1] * K[1][j]
                                  + u[2] * K[2][j] + u[3] * K[3][j];
                    v[j] = v[j] * __builtin_amdgcn_rcpf(fmaf(v[j], S, 1e-8f));
                }
                #pragma unroll
                for (int i = 0; i < 4; ++i) {
                    const float T = K[i][0] * v[0] + K[i][1] * v[1]
                                  + K[i][2] * v[2] + K[i][3] * v[3];
                    u[i] = u[i] * __builtin_amdgcn_rcpf(fmaf(u[i], T, 1e-8f));
                }
            }
            #pragma unroll
            for (int i = 0; i < 4; ++i)
                #pragma unroll
                for (int j = 0; j < 4; ++j)
                    Mlds[tk * 16 + 4 * i + j] =
                        fmaf(u[i] * K[i][j], v[j], hpost[i] * hpre[j]);
        }
        __syncthreads();

        // ---- phase 4: mixing, out[i][c] = sum_j M[i][j] * x[j][c] ----
        for (int i = 0; i < G; ++i) {
            const float4 m4 = ((const float4*)Mlds)[i * 4 + w];  // row w, broadcast
            const float4* xt = xs4 + i * 256;
            const float4 a0 = xt[0 * 64 + l];
            const float4 a1 = xt[1 * 64 + l];
            const float4 a2 = xt[2 * 64 + l];
            const float4 a3 = xt[3 * 64 + l];
            float4 o;
            o.x = m4.x * a0.x + m4.y * a1.x + m4.z * a2.x + m4.w * a3.x;
            o.y = m4.x * a0.y + m4.y * a1.y + m4.z * a2.y + m4.w * a3.y;
            o.z = m4.x * a0.z + m4.y * a1.z + m4.z * a2.z + m4.w * a3.z;
            o.w = m4.x * a0.w + m4.y * a1.w + m4.z * a2.w + m4.w * a3.w;
            ((float4*)(out + base))[i * 256 + w * 64 + l] = o;
        }
        __syncthreads();  // protect xs before next round's staging
    }
}

extern "C" void kernel_launch(void* const* d_in, const int* in_sizes, int n_in,
                              void* d_out, int out_size, void* d_ws, size_t ws_size,
                              hipStream_t stream) {
    const float* x      = (const float*)d_in[0];
    const float* scale  = (const float*)d_in[1];
    const float* w_pre  = (const float*)d_in[2];
    const float* w_post = (const float*)d_in[3];
    const float* w_res  = (const float*)d_in[4];
    const float* a_pre  = (const float*)d_in[5];
    const float* a_post = (const float*)d_in[6];
    const float* a_res  = (const float*)d_in[7];
    const float* b_pre  = (const float*)d_in[8];
    const float* b_post = (const float*)d_in[9];
    const float* b_res  = (const float*)d_in[10];
    float* out = (float*)d_out;

    const int tokens = in_sizes[0] / 1024;   // B*T (n*C = 1024)
    const int rounds = tokens / G;
    // grid = 512 -> exactly 2 resident blocks/CU on 256 CUs, 4 rounds/block:
    // only the first round per block pays an unhidden prefetch.
    const int grid = rounds < 512 ? rounds : 512;

    fused_route_mix<<<grid, 256, 0, stream>>>(
        x, scale, w_pre, w_post, w_res,
        a_pre, a_post, a_res, b_pre, b_post, b_res,
        out, rounds);
}

// Round 2
// 292.972 us; speedup vs baseline: 1.0535x; 1.0535x over previous
//
#include <hip/hip_runtime.h>
#include <math.h>

#define G 8  // tokens per round; LDS = 2*32KB xs + ~0.8KB small = ~66KB -> 2 blocks/CU

__device__ __forceinline__ float sigmoidf_(float s) {
    return 1.0f / (1.0f + __expf(-s));
}

// Pair-fold reduction step: lanes with (l&m)==0 get X(l)+X(l^m),
// lanes with (l&m)!=0 get Y(l)+Y(l^m).
__device__ __forceinline__ float fold_(float X, float Y, int m, int l) {
    const bool hi = (l & m) != 0;
    const float a = hi ? Y : X;
    const float b = hi ? X : Y;
    return a + __shfl_xor(b, m);
}

// async global->LDS DMA: each lane copies 16B from its own gsrc to
// wave-uniform LDS base + lane*16 (linear layout, exactly what we want).
__device__ __forceinline__ void gll16(const float4* g, float* lds) {
    __builtin_amdgcn_global_load_lds(
        (const __attribute__((address_space(1))) void*)g,
        (__attribute__((address_space(3))) void*)lds, 16, 0, 0);
}

__global__ __launch_bounds__(256)
__attribute__((amdgpu_waves_per_eu(2, 2)))   // pin 2 waves/EU -> VGPR budget 256, no spill
void fused_route_mix(const float* __restrict__ x,
                     const float* __restrict__ scale,
                     const float* __restrict__ w_pre,
                     const float* __restrict__ w_post,
                     const float* __restrict__ w_res,
                     const float* __restrict__ ap_p,
                     const float* __restrict__ apo_p,
                     const float* __restrict__ ar_p,
                     const float* __restrict__ b_pre,
                     const float* __restrict__ b_post,
                     const float* __restrict__ b_res,
                     float* __restrict__ out,
                     int rounds)
{
    __shared__ __align__(16) float xs[2][G * 1024];  // double-buffered raw x
    __shared__ __align__(16) float hraw[G * 24];     // 24 raw dots per token
    __shared__ float sslds[G];                       // sum of squares per token

    const int t = threadIdx.x;
    const int w = t >> 6;   // wave 0..3
    const int l = t & 63;   // lane 0..63

    // ---- once per block: weight fragments in registers (scale folded in) ----
    // global row k: 0-3 = w_pre, 4-7 = w_post, 8-23 = w_res. wave w owns rows 6w..6w+5.
    // lane l owns elements {4*l + 256*mp + j : mp=0..3, j=0..3} -> float4 LDS reads.
    float wreg[6][16];
    {
        float scl[16];
        #pragma unroll
        for (int mp = 0; mp < 4; ++mp)
            #pragma unroll
            for (int j = 0; j < 4; ++j)
                scl[4 * mp + j] = scale[4 * l + 256 * mp + j];
        #pragma unroll
        for (int rr = 0; rr < 6; ++rr) {
            const int k = 6 * w + rr;
            const float* wp = (k < 4) ? (w_pre + (size_t)k * 1024)
                            : (k < 8) ? (w_post + (size_t)(k - 4) * 1024)
                                      : (w_res + (size_t)(k - 8) * 1024);
            #pragma unroll
            for (int mp = 0; mp < 4; ++mp)
                #pragma unroll
                for (int j = 0; j < 4; ++j)
                    wreg[rr][4 * mp + j] = wp[4 * l + 256 * mp + j] * scl[4 * mp + j];
        }
    }

    const float a_pre = ap_p[0], a_post = apo_p[0], a_res = ar_p[0];
    float bp[4], bpo[4], br[16];
    #pragma unroll
    for (int k = 0; k < 4; ++k) { bp[k] = b_pre[k]; bpo[k] = b_post[k]; }
    #pragma unroll
    for (int k = 0; k < 16; ++k) br[k] = b_res[k];

    const int rstep = gridDim.x;
    int cur = 0;

    // ---- prologue: async-prefetch first round into buffer 0 ----
    {
        const float4* __restrict__ xg =
            (const float4*)(x + (size_t)blockIdx.x * (G * 1024));
        #pragma unroll
        for (int i = 0; i < G; ++i)
            gll16(xg + i * 256 + (w << 6) + l, &xs[0][i * 1024 + (w << 8)]);
    }

    for (int r = blockIdx.x; r < rounds; r += rstep) {
        const size_t base = (size_t)r * (G * 1024);

        // B1: full drain — prefetch into xs[cur] landed; xs[cur^1] + hraw free.
        __syncthreads();

        // ---- issue next round's async loads into the other buffer;
        //      they stay in flight across the ENTIRE round (B2 doesn't drain vmcnt) ----
        const int rn = r + rstep;
        if (rn < rounds) {
            const float4* __restrict__ xg =
                (const float4*)(x + (size_t)rn * (G * 1024));
            #pragma unroll
            for (int i = 0; i < G; ++i)
                gll16(xg + i * 256 + (w << 6) + l, &xs[cur ^ 1][i * 1024 + (w << 8)]);
        }

        const float* __restrict__ xb = xs[cur];

        // ---- phase 2: 24 raw dot products + sum-of-squares per token ----
        for (int i = 0; i < G; ++i) {
            float p0 = 0.f, p1 = 0.f, p2 = 0.f, p3 = 0.f, p4 = 0.f, p5 = 0.f;
            float ss = 0.f;
            const float4* __restrict__ xi4 = (const float4*)(xb + i * 1024);
            #pragma unroll
            for (int mp = 0; mp < 4; ++mp) {
                const float4 xv = xi4[l + 64 * mp];   // ds_read_b128, conflict-free
                const float xe[4] = {xv.x, xv.y, xv.z, xv.w};
                #pragma unroll
                for (int j = 0; j < 4; ++j) {
                    const float xj = xe[j];
                    p0 = fmaf(xj, wreg[0][4 * mp + j], p0);
                    p1 = fmaf(xj, wreg[1][4 * mp + j], p1);
                    p2 = fmaf(xj, wreg[2][4 * mp + j], p2);
                    p3 = fmaf(xj, wreg[3][4 * mp + j], p3);
                    p4 = fmaf(xj, wreg[4][4 * mp + j], p4);
                    p5 = fmaf(xj, wreg[5][4 * mp + j], p5);
                    ss = fmaf(xj, xj, ss);            // same across waves; wave0 writes
                }
            }
            // pack-fold butterfly: 10 shfl instead of 42.
            const float q0 = fold_(p0, p1, 32, l);
            const float q1 = fold_(p2, p3, 32, l);
            const float q2 = fold_(p4, p5, 32, l);
            const float q3 = ss + __shfl_xor(ss, 32);
            const float r0v = fold_(q0, q1, 16, l);
            const float r1v = fold_(q2, q3, 16, l);
            float s = fold_(r0v, r1v, 8, l);
            s += __shfl_xor(s, 4);
            s += __shfl_xor(s, 2);
            s += __shfl_xor(s, 1);
            // lanes 0,8,16,24,32,40,48 hold fully-reduced values:
            // vid: 0=p0(l0) 1=p1(l32) 2=p2(l16) 3=p3(l48) 4=p4(l8) 5=p5(l40) 6=ss(l24)
            if ((l & 7) == 0) {
                const int vid = ((l >> 3) & 1) * 4 + ((l >> 4) & 1) * 2 + ((l >> 5) & 1);
                if (vid < 6) hraw[i * 24 + 6 * w + vid] = s;
                else if (w == 0 && vid == 6) sslds[i] = s;
            }
        }

        // B2: LDS-only barrier — waits ds_writes (lgkm) but leaves the
        // prefetch (vmcnt) in flight until the next B1.
        asm volatile("s_waitcnt lgkmcnt(0)\n\ts_barrier" ::: "memory");

        // ---- phase 3: per-token nonlinearity + sinkhorn ----
        // ALL lanes compute redundantly (lane -> token l&7); each wave keeps only
        // its row M[w][*]. No barrier / LDS round-trip needed before phase 4.
        float Mw0, Mw1, Mw2, Mw3;
        {
            const int tk = l & (G - 1);
            const float inv = rsqrtf(sslds[tk] * (1.0f / 1024.0f) + 1e-5f);
            float hr[24];
            const float4* __restrict__ hp = (const float4*)(hraw + tk * 24);
            #pragma unroll
            for (int q = 0; q < 6; ++q) {
                const float4 hv = hp[q];
                hr[4 * q + 0] = hv.x; hr[4 * q + 1] = hv.y;
                hr[4 * q + 2] = hv.z; hr[4 * q + 3] = hv.w;
            }

            float hpre[4], hpost[4];
            #pragma unroll
            for (int j = 0; j < 4; ++j)
                hpre[j] = sigmoidf_(fmaf(a_pre * inv, hr[j], bp[j]));
            #pragma unroll
            for (int i = 0; i < 4; ++i)
                hpost[i] = 2.0f * sigmoidf_(fmaf(a_post * inv, hr[4 + i], bpo[i]));

            float K[4][4];
            float mx = -1e30f;
            #pragma unroll
            for (int i = 0; i < 4; ++i)
                #pragma unroll
                for (int j = 0; j < 4; ++j) {
                    const float vv = fmaf(a_res * inv, hr[8 + 4 * i + j], br[4 * i + j]);
                    K[i][j] = vv;
                    mx = fmaxf(mx, vv);
                }
            #pragma unroll
            for (int i = 0; i < 4; ++i)
                #pragma unroll
                for (int j = 0; j < 4; ++j)
                    K[i][j] = __expf(K[i][j] - mx);

            // sinkhorn as scaling vectors: matrix is u_i * K_ij * v_j throughout.
            float u[4] = {1.f, 1.f, 1.f, 1.f};
            float v[4] = {1.f, 1.f, 1.f, 1.f};
            for (int it = 0; it < 20; ++it) {
                #pragma unroll
                for (int j = 0; j < 4; ++j) {
                    const float S = u[0] * K[0][j] + u[1] * K[1][j]
                                  + u[2] * K[2][j] + u[3] * K[3][j];
                    v[j] = v[j] * __builtin_amdgcn_rcpf(fmaf(v[j], S, 1e-8f));
                }
                #pragma unroll
                for (int i = 0; i < 4; ++i) {
                    const float T = K[i][0] * v[0] + K[i][1] * v[1]
                                  + K[i][2] * v[2] + K[i][3] * v[3];
                    u[i] = u[i] * __builtin_amdgcn_rcpf(fmaf(u[i], T, 1e-8f));
                }
            }

            // wave-uniform row select (3 cndmasks per value, no dynamic indexing)
            const float uw  = (w == 0) ? u[0] : (w == 1) ? u[1] : (w == 2) ? u[2] : u[3];
            const float hpw = (w == 0) ? hpost[0] : (w == 1) ? hpost[1]
                            : (w == 2) ? hpost[2] : hpost[3];
            #define KW(j) ((w == 0) ? K[0][j] : (w == 1) ? K[1][j] : (w == 2) ? K[2][j] : K[3][j])
            Mw0 = fmaf(uw * KW(0), v[0], hpw * hpre[0]);
            Mw1 = fmaf(uw * KW(1), v[1], hpw * hpre[1]);
            Mw2 = fmaf(uw * KW(2), v[2], hpw * hpre[2]);
            Mw3 = fmaf(uw * KW(3), v[3], hpw * hpre[3]);
            #undef KW
        }

        // ---- phase 4: mixing, out[i][c] = sum_j M[i][j] * x[j][c] ----
        for (int i = 0; i < G; ++i) {
            const float m0 = __shfl(Mw0, i);   // token i sits on lane i
            const float m1 = __shfl(Mw1, i);
            const float m2 = __shfl(Mw2, i);
            const float m3 = __shfl(Mw3, i);
            const float4* __restrict__ xt = (const float4*)(xb + i * 1024);
            const float4 a0 = xt[0 * 64 + l];
            const float4 a1 = xt[1 * 64 + l];
            const float4 a2 = xt[2 * 64 + l];
            const float4 a3 = xt[3 * 64 + l];
            float4 o;
            o.x = m0 * a0.x + m1 * a1.x + m2 * a2.x + m3 * a3.x;
            o.y = m0 * a0.y + m1 * a1.y + m2 * a2.y + m3 * a3.y;
            o.z = m0 * a0.z + m1 * a1.z + m2 * a2.z + m3 * a3.z;
            o.w = m0 * a0.w + m1 * a1.w + m2 * a2.w + m3 * a3.w;
            ((float4*)(out + base))[i * 256 + (w << 6) + l] = o;
        }

        cur ^= 1;
    }
}

extern "C" void kernel_launch(void* const* d_in, const int* in_sizes, int n_in,
                              void* d_out, int out_size, void* d_ws, size_t ws_size,
                              hipStream_t stream) {
    const float* x      = (const float*)d_in[0];
    const float* scale  = (const float*)d_in[1];
    const float* w_pre  = (const float*)d_in[2];
    const float* w_post = (const float*)d_in[3];
    const float* w_res  = (const float*)d_in[4];
    const float* a_pre  = (const float*)d_in[5];
    const float* a_post = (const float*)d_in[6];
    const float* a_res  = (const float*)d_in[7];
    const float* b_pre  = (const float*)d_in[8];
    const float* b_post = (const float*)d_in[9];
    const float* b_res  = (const float*)d_in[10];
    float* out = (float*)d_out;

    const int tokens = in_sizes[0] / 1024;   // B*T (n*C = 1024)
    const int rounds = tokens / G;
    // grid = 512 -> exactly 2 resident blocks/CU on 256 CUs.
    const int grid = rounds < 512 ? rounds : 512;

    fused_route_mix<<<grid, 256, 0, stream>>>(
        x, scale, w_pre, w_post, w_res,
        a_pre, a_post, a_res, b_pre, b_post, b_res,
        out, rounds);
}

// Round 3
// 282.917 us; speedup vs baseline: 1.0910x; 1.0355x over previous
//
#include <hip/hip_runtime.h>
#include <math.h>

#define G 8   // tokens per round
// 512 threads = 8 waves; wave w owns weight rows 3w..3w+2 (24 rows total).
// LDS: 2*32KB xs + 768B hraw + 32B ss + 512B M ~= 66.6KB -> 2 blocks/CU.
// waves_per_eu(4,4) pins VGPR <= 128 -> 16 waves/CU = 4 waves/SIMD.

__device__ __forceinline__ float sigmoidf_(float s) {
    return 1.0f / (1.0f + __expf(-s));
}

// Pair-fold reduction step: lanes with (l&m)==0 get X(l)+X(l^m),
// lanes with (l&m)!=0 get Y(l)+Y(l^m).
__device__ __forceinline__ float fold_(float X, float Y, int m, int l) {
    const bool hi = (l & m) != 0;
    const float a = hi ? Y : X;
    const float b = hi ? X : Y;
    return a + __shfl_xor(b, m);
}

// async global->LDS DMA: each lane copies 16B; LDS dest = wave-uniform base + lane*16.
__device__ __forceinline__ void gll16(const float4* g, const float* lds) {
    __builtin_amdgcn_global_load_lds(
        (const __attribute__((address_space(1))) void*)g,
        (__attribute__((address_space(3))) void*)lds, 16, 0, 0);
}

__global__ __launch_bounds__(512)
__attribute__((amdgpu_waves_per_eu(4, 4)))
void fused_route_mix(const float* __restrict__ x,
                     const float* __restrict__ scale,
                     const float* __restrict__ w_pre,
                     const float* __restrict__ w_post,
                     const float* __restrict__ w_res,
                     const float* __restrict__ ap_p,
                     const float* __restrict__ apo_p,
                     const float* __restrict__ ar_p,
                     const float* __restrict__ b_pre,
                     const float* __restrict__ b_post,
                     const float* __restrict__ b_res,
                     float* __restrict__ out,
                     int rounds)
{
    __shared__ __align__(16) float xs[2][G * 1024];  // double-buffered raw x
    __shared__ __align__(16) float hraw[G * 24];     // 24 raw dots per token
    __shared__ float sslds[G];                       // sum of squares per token
    __shared__ __align__(16) float Mlds[G * 16];     // 4x4 mixing matrix per token

    const int t = threadIdx.x;
    const int w = t >> 6;   // wave 0..7
    const int l = t & 63;   // lane 0..63

    // ---- once per block: 3 weight rows per wave, scale folded in ----
    // lane l owns elements {4l + 256mp + j : mp=0..3, j=0..3} -> float4 LDS reads.
    float wreg[3][16];
    #pragma unroll
    for (int rr = 0; rr < 3; ++rr) {
        const int k = 3 * w + rr;
        const float* wp = (k < 4) ? (w_pre + (size_t)k * 1024)
                        : (k < 8) ? (w_post + (size_t)(k - 4) * 1024)
                                  : (w_res + (size_t)(k - 8) * 1024);
        #pragma unroll
        for (int mp = 0; mp < 4; ++mp)
            #pragma unroll
            for (int j = 0; j < 4; ++j)
                wreg[rr][4 * mp + j] =
                    wp[4 * l + 256 * mp + j] * scale[4 * l + 256 * mp + j];
    }

    const int rstep = gridDim.x;
    int cur = 0;

    // ---- prologue: async-prefetch first round into buffer 0 ----
    {
        const float4* __restrict__ xg =
            (const float4*)(x + (size_t)blockIdx.x * (G * 1024));
        #pragma unroll
        for (int i = 0; i < 4; ++i)
            gll16(xg + i * 512 + t, &xs[0][i * 2048 + (w << 8)]);
    }

    for (int r = blockIdx.x; r < rounds; r += rstep) {
        const size_t base = (size_t)r * (G * 1024);

        // B1: full drain — prefetch into xs[cur] landed; other buffers free.
        __syncthreads();

        // issue next round's DMA into the other buffer; stays in flight all round
        const int rn = r + rstep;
        if (rn < rounds) {
            const float4* __restrict__ xg =
                (const float4*)(x + (size_t)rn * (G * 1024));
            #pragma unroll
            for (int i = 0; i < 4; ++i)
                gll16(xg + i * 512 + t, &xs[cur ^ 1][i * 2048 + (w << 8)]);
        }

        const float* __restrict__ xb = xs[cur];

        // ---- phase 2: 3 dots + ss per wave per token ----
        #pragma unroll 2
        for (int i = 0; i < G; ++i) {
            float p0 = 0.f, p1 = 0.f, p2 = 0.f, ss = 0.f;
            const float4* __restrict__ xi4 = (const float4*)(xb + i * 1024);
            #pragma unroll
            for (int mp = 0; mp < 4; ++mp) {
                const float4 xv = xi4[l + 64 * mp];   // ds_read_b128, conflict-free
                const float xe[4] = {xv.x, xv.y, xv.z, xv.w};
                #pragma unroll
                for (int j = 0; j < 4; ++j) {
                    const float xj = xe[j];
                    p0 = fmaf(xj, wreg[0][4 * mp + j], p0);
                    p1 = fmaf(xj, wreg[1][4 * mp + j], p1);
                    p2 = fmaf(xj, wreg[2][4 * mp + j], p2);
                    ss = fmaf(xj, xj, ss);            // only wave 0 writes it
                }
            }
            // pack-fold butterfly: 7 shfl for 4 values
            const float q0 = fold_(p0, p1, 32, l);
            const float q1 = fold_(p2, ss, 32, l);
            float s = fold_(q0, q1, 16, l);
            s += __shfl_xor(s, 8);
            s += __shfl_xor(s, 4);
            s += __shfl_xor(s, 2);
            s += __shfl_xor(s, 1);
            // lane 0 -> p0, lane 32 -> p1, lane 16 -> p2, lane 48 -> ss
            if ((l & 15) == 0) {
                const int vid = ((l >> 5) & 1) | (((l >> 4) & 1) << 1);
                if (vid < 3) hraw[i * 24 + 3 * w + vid] = s;
                else if (w == 0) sslds[i] = s;
            }
        }

        // B2: LDS-only barrier — keeps prefetch (vmcnt) in flight.
        asm volatile("s_waitcnt lgkmcnt(0)\n\ts_barrier" ::: "memory");

        // ---- phase 3: sinkhorn on wave 0 only (lane -> token l&7) ----
        if (w == 0) {
            const int tk = l & (G - 1);
            const float inv = rsqrtf(sslds[tk] * (1.0f / 1024.0f) + 1e-5f);
            float hr[24];
            const float4* __restrict__ hp = (const float4*)(hraw + tk * 24);
            #pragma unroll
            for (int q = 0; q < 6; ++q) {
                const float4 hv = hp[q];
                hr[4 * q + 0] = hv.x; hr[4 * q + 1] = hv.y;
                hr[4 * q + 2] = hv.z; hr[4 * q + 3] = hv.w;
            }
            const float a_pre = ap_p[0], a_post = apo_p[0], a_res = ar_p[0];

            float hpre[4], hpost[4];
            #pragma unroll
            for (int j = 0; j < 4; ++j)
                hpre[j] = sigmoidf_(fmaf(a_pre * inv, hr[j], b_pre[j]));
            #pragma unroll
            for (int i = 0; i < 4; ++i)
                hpost[i] = 2.0f * sigmoidf_(fmaf(a_post * inv, hr[4 + i], b_post[i]));

            float K[4][4];
            float mx = -1e30f;
            #pragma unroll
            for (int i = 0; i < 4; ++i)
                #pragma unroll
                for (int j = 0; j < 4; ++j) {
                    const float vv = fmaf(a_res * inv, hr[8 + 4 * i + j], b_res[4 * i + j]);
                    K[i][j] = vv;
                    mx = fmaxf(mx, vv);
                }
            #pragma unroll
            for (int i = 0; i < 4; ++i)
                #pragma unroll
                for (int j = 0; j < 4; ++j)
                    K[i][j] = __expf(K[i][j] - mx);

            // sinkhorn as scaling vectors: matrix is u_i * K_ij * v_j throughout.
            float u[4] = {1.f, 1.f, 1.f, 1.f};
            float v[4] = {1.f, 1.f, 1.f, 1.f};
            for (int it = 0; it < 20; ++it) {
                #pragma unroll
                for (int j = 0; j < 4; ++j) {
                    const float S = (fmaf(u[0], K[0][j], u[1] * K[1][j]))
                                  + (fmaf(u[2], K[2][j], u[3] * K[3][j]));
                    v[j] = v[j] * __builtin_amdgcn_rcpf(fmaf(v[j], S, 1e-8f));
                }
                #pragma unroll
                for (int i = 0; i < 4; ++i) {
                    const float T = (fmaf(K[i][0], v[0], K[i][1] * v[1]))
                                  + (fmaf(K[i][2], v[2], K[i][3] * v[3]));
                    u[i] = u[i] * __builtin_amdgcn_rcpf(fmaf(u[i], T, 1e-8f));
                }
            }

            if (l < G) {   // lane l computed token l exactly
                float4* Md = (float4*)(Mlds + (l << 4));
                #pragma unroll
                for (int i2 = 0; i2 < 4; ++i2) {
                    float4 row;
                    row.x = fmaf(u[i2] * K[i2][0], v[0], hpost[i2] * hpre[0]);
                    row.y = fmaf(u[i2] * K[i2][1], v[1], hpost[i2] * hpre[1]);
                    row.z = fmaf(u[i2] * K[i2][2], v[2], hpost[i2] * hpre[2]);
                    row.w = fmaf(u[i2] * K[i2][3], v[3], hpost[i2] * hpre[3]);
                    Md[i2] = row;
                }
            }
        }

        // B3: LDS-only barrier — Mlds visible, vmcnt still in flight.
        asm volatile("s_waitcnt lgkmcnt(0)\n\ts_barrier" ::: "memory");

        // ---- phase 4: out[i][c] = sum_j M[i][j] * x[j][c] ----
        // thread handles output stream (w&3), tokens {half, half+2, half+4, half+6}
        const int w4 = w & 3;
        const int half = t >> 8;
        #pragma unroll
        for (int ii = 0; ii < 4; ++ii) {
            const int i = 2 * ii + half;
            const float4 m4 = ((const float4*)Mlds)[(i << 2) + w4];  // broadcast
            const float4* __restrict__ xt = (const float4*)(xb + i * 1024);
            const float4 a0 = xt[0 * 64 + l];
            const float4 a1 = xt[1 * 64 + l];
            const float4 a2 = xt[2 * 64 + l];
            const float4 a3 = xt[3 * 64 + l];
            float4 o;
            o.x = m4.x * a0.x + m4.y * a1.x + m4.z * a2.x + m4.w * a3.x;
            o.y = m4.x * a0.y + m4.y * a1.y + m4.z * a2.y + m4.w * a3.y;
            o.z = m4.x * a0.z + m4.y * a1.z + m4.z * a2.z + m4.w * a3.z;
            o.w = m4.x * a0.w + m4.y * a1.w + m4.z * a2.w + m4.w * a3.w;
            ((float4*)(out + base))[(i << 8) + (w4 << 6) + l] = o;
        }

        cur ^= 1;
    }
}

extern "C" void kernel_launch(void* const* d_in, const int* in_sizes, int n_in,
                              void* d_out, int out_size, void* d_ws, size_t ws_size,
                              hipStream_t stream) {
    const float* x      = (const float*)d_in[0];
    const float* scale  = (const float*)d_in[1];
    const float* w_pre  = (const float*)d_in[2];
    const float* w_post = (const float*)d_in[3];
    const float* w_res  = (const float*)d_in[4];
    const float* a_pre  = (const float*)d_in[5];
    const float* a_post = (const float*)d_in[6];
    const float* a_res  = (const float*)d_in[7];
    const float* b_pre  = (const float*)d_in[8];
    const float* b_post = (const float*)d_in[9];
    const float* b_res  = (const float*)d_in[10];
    float* out = (float*)d_out;

    const int tokens = in_sizes[0] / 1024;   // B*T (n*C = 1024)
    const int rounds = tokens / G;
    // 512 blocks x 512 threads -> exactly 2 blocks/CU on 256 CUs.
    const int grid = rounds < 512 ? rounds : 512;

    fused_route_mix<<<grid, 512, 0, stream>>>(
        x, scale, w_pre, w_post, w_res,
        a_pre, a_post, a_res, b_pre, b_post, b_res,
        out, rounds);
}